// Round 1
// baseline (604.629 us; speedup 1.0000x reference)
//
#include <hip/hip_runtime.h>

// LSTM forward, fused: T=2048, B=1024, I=15, H=10, gates=40 (PyTorch order i,f,g,o).
// One wave (64 threads) per batch row. Lane g<40 owns gate g.
// Serial over T; parallel over B (1024 waves ~ 1 wave/SIMD on MI355X).

#define T_N 2048
#define B_N 1024
#define I_N 15
#define H_N 10
#define G_N 40
#define DQ 8  // x prefetch queue depth

static __device__ __forceinline__ float rl(float v, int lane) {
    return __builtin_bit_cast(float, __builtin_amdgcn_readlane(__builtin_bit_cast(int, v), lane));
}
static __device__ __forceinline__ float bperm(int addrB, float v) {
    return __builtin_bit_cast(float, __builtin_amdgcn_ds_bpermute(addrB, __builtin_bit_cast(int, v)));
}

__global__ __launch_bounds__(64) void lstm_fused(
    const float* __restrict__ x, const float* __restrict__ h0,
    const float* __restrict__ c0, const float* __restrict__ Wih,
    const float* __restrict__ Whh, float* __restrict__ out)
{
    const int b = blockIdx.x;
    const int lane = threadIdx.x;
    const int g = lane < G_N ? lane : G_N - 1;   // clamp idle lanes 40..63
    const int j = lane % H_N;                    // hidden unit this lane tracks c/h for
    const bool isTanhGate = (g >= 20 && g < 30); // 'g' gate rows
    const float LOG2E = 1.4426950408889634f;
    // Fold activation-argument scale into the weight rows:
    //  sigmoid(z) = 1/(1+exp2(-z*log2e))   -> scale = -log2e
    //  tanh(z)    = 1 - 2/(1+exp2(2z*log2e)) -> scale = +2*log2e
    const float sg   = isTanhGate ? 2.0f * LOG2E : -LOG2E;
    const float Aact = isTanhGate ? -2.0f : 1.0f;
    const float Bact = isTanhGate ?  1.0f : 0.0f;

    // Prescaled weight rows in registers
    float wih[I_N];
#pragma unroll
    for (int i = 0; i < I_N; ++i) wih[i] = sg * Wih[g * I_N + i];
    float whh[H_N];
#pragma unroll
    for (int q = 0; q < H_N; ++q) whh[q] = sg * Whh[g * H_N + q];

    // Initial state
    float c  = c0[b * H_N + j];
    float hj = h0[b * H_N + j];
    float hs[H_N];  // wave-uniform (SGPR) copies of h[0..9]
#pragma unroll
    for (int q = 0; q < H_N; ++q) hs[q] = rl(hj, q);

    // bpermute byte addresses for gate combine (i,f,g,o of hidden unit j)
    const int ai = 4 * j, af = 4 * (j + 10), ag = 4 * (j + 20), ao = 4 * (j + 30);

    // x prefetch queue: lanes 0..14 carry x[t][b][lane]; others dup x[..][0] (same cacheline)
    const int xk = lane < I_N ? lane : 0;
    float xq[DQ];
#pragma unroll
    for (int d = 0; d < DQ; ++d)
        xq[d] = x[((size_t)d * B_N + b) * I_N + xk];

    float hlast = 0.0f;

    for (int t0 = 0; t0 < T_N; t0 += DQ) {
#pragma unroll
        for (int d = 0; d < DQ; ++d) {
            const int t = t0 + d;
            const float xv = xq[d];
            // refill queue (clamped at tail; redundant loads are harmless)
            int tq = t + DQ; if (tq > T_N - 1) tq = T_N - 1;
            xq[d] = x[((size_t)tq * B_N + b) * I_N + xk];

            // gate pre-activation: 5 independent FMA chains, then tree-add
            float a0 = 0.f, a1 = 0.f, a2 = 0.f, a3 = 0.f, a4 = 0.f;
#pragma unroll
            for (int k = 0; k < 5; ++k)  a0 = fmaf(rl(xv, k),      wih[k],      a0);
#pragma unroll
            for (int k = 0; k < 5; ++k)  a1 = fmaf(rl(xv, k + 5),  wih[k + 5],  a1);
#pragma unroll
            for (int k = 0; k < 5; ++k)  a2 = fmaf(rl(xv, k + 10), wih[k + 10], a2);
#pragma unroll
            for (int q = 0; q < 5; ++q)  a3 = fmaf(hs[q],          whh[q],      a3);
#pragma unroll
            for (int q = 0; q < 5; ++q)  a4 = fmaf(hs[q + 5],      whh[q + 5],  a4);
            const float acc = ((a0 + a1) + (a2 + a3)) + a4;

            // activation: r = 1/(1+exp2(acc)); sigmoid -> r, tanh -> 1-2r
            const float e   = __builtin_amdgcn_exp2f(acc);
            const float r   = __builtin_amdgcn_rcpf(1.0f + e);
            const float act = fmaf(Aact, r, Bact);

            // gather i,f,g,o for hidden unit j
            const float iv = bperm(ai, act);
            const float fv = bperm(af, act);
            const float gv = bperm(ag, act);
            const float ov = bperm(ao, act);

            // cell + hidden update
            c = fmaf(fv, c, iv * gv);
            const float tt = __builtin_amdgcn_exp2f(c * (2.0f * LOG2E));
            const float rr = __builtin_amdgcn_rcpf(1.0f + tt);
            const float th = fmaf(-2.0f, rr, 1.0f);
            const float h  = ov * th;
            hlast = h;

            if (lane < H_N)
                out[(size_t)t * (B_N * H_N) + b * H_N + lane] = h;

            // broadcast new h to SGPRs for next step
#pragma unroll
            for (int q = 0; q < H_N; ++q) hs[q] = rl(h, q);
        }
    }

    // final hN, cN appended after out (flat tuple order: out, hN, cN)
    if (lane < H_N) {
        const size_t base = (size_t)T_N * B_N * H_N;
        out[base + b * H_N + lane] = hlast;              // hN
        out[base + (size_t)B_N * H_N + b * H_N + lane] = c;  // cN
    }
}

extern "C" void kernel_launch(void* const* d_in, const int* in_sizes, int n_in,
                              void* d_out, int out_size, void* d_ws, size_t ws_size,
                              hipStream_t stream) {
    const float* x   = (const float*)d_in[0];
    const float* h0  = (const float*)d_in[1];
    const float* c0  = (const float*)d_in[2];
    const float* Wih = (const float*)d_in[3];
    const float* Whh = (const float*)d_in[4];
    float* out = (float*)d_out;
    lstm_fused<<<dim3(B_N), dim3(64), 0, stream>>>(x, h0, c0, Wih, Whh, out);
}

// Round 2
// 548.507 us; speedup vs baseline: 1.1023x; 1.1023x over previous
//
#include <hip/hip_runtime.h>

// LSTM forward, fused: T=2048, B=1024, I=15, H=10 (PyTorch gate order i,f,g,o).
// One wave per batch row; 1024 waves = 1/SIMD (structural; serial over T).
// Lane layout: lane = 4*j + p, j=hidden unit (0..9 -> lanes 0..39), p=gate.
// Gate combine via DPP quad_perm broadcasts (VALU latency, no LDS pipe).

#define T_N 2048
#define B_N 1024
#define I_N 15
#define H_N 10
#define DQ 8  // x prefetch queue depth

template <int CTRL>
static __device__ __forceinline__ float qb(float v) {
    // quad_perm broadcast within each group of 4 lanes
    return __builtin_bit_cast(float,
        __builtin_amdgcn_mov_dpp(__builtin_bit_cast(int, v), CTRL, 0xF, 0xF, true));
}
static __device__ __forceinline__ float rl(float v, int lane) {
    return __builtin_bit_cast(float, __builtin_amdgcn_readlane(__builtin_bit_cast(int, v), lane));
}

__global__ __launch_bounds__(64, 1) void lstm_fused(
    const float* __restrict__ x, const float* __restrict__ h0,
    const float* __restrict__ c0, const float* __restrict__ Wih,
    const float* __restrict__ Whh, float* __restrict__ out)
{
    const int b = blockIdx.x;
    const int lane = threadIdx.x;
    const int p = lane & 3;              // gate: 0=i 1=f 2=g 3=o
    int j = lane >> 2; if (j > H_N - 1) j = H_N - 1;  // hidden unit (lanes 40..63 dup j=9)
    const int row = p * H_N + j;         // W row (PyTorch: [i;f;g;o] blocks of 10)
    const bool isTanh = (p == 2);
    const float LOG2E = 1.4426950408889634f;
    // Fold activation-argument scale into the weight rows:
    //  sigmoid(z) = 1/(1+exp2(-z*log2e))     -> scale = -log2e,  act = r
    //  tanh(z)    = 1 - 2/(1+exp2(2z*log2e)) -> scale = +2log2e, act = 1-2r
    const float sg   = isTanh ? 2.0f * LOG2E : -LOG2E;
    const float Aact = isTanh ? -2.0f : 1.0f;
    const float Bact = isTanh ?  1.0f : 0.0f;

    float wih[I_N];
#pragma unroll
    for (int i = 0; i < I_N; ++i) wih[i] = sg * Wih[row * I_N + i];
    float whh[H_N];
#pragma unroll
    for (int q = 0; q < H_N; ++q) whh[q] = sg * Whh[row * H_N + q];

    // Every lane of quad j tracks c/h for unit j (redundant, divergence-free)
    float c = c0[b * H_N + j];
    float h = h0[b * H_N + j];
    float hs[H_N];  // wave-uniform SGPR copies of h[0..9] (unit q lives at lane 4q)
#pragma unroll
    for (int q = 0; q < H_N; ++q) hs[q] = rl(h, 4 * q);

    // x prefetch queue: lanes 0..14 carry x[t][b][lane]; others dup element 0
    const int xk = lane < I_N ? lane : 0;
    float xq[DQ];
#pragma unroll
    for (int d = 0; d < DQ; ++d)
        xq[d] = x[((size_t)d * B_N + b) * I_N + xk];

    const bool writer = ((lane & 3) == 0) && (lane < 4 * H_N);

    for (int t0 = 0; t0 < T_N; t0 += DQ) {
#pragma unroll
        for (int d = 0; d < DQ; ++d) {
            const int t = t0 + d;
            const float xv = xq[d];
            int tq = t + DQ; if (tq > T_N - 1) tq = T_N - 1;
            xq[d] = x[((size_t)tq * B_N + b) * I_N + xk];

            // x contribution (off the recurrent chain; prefetched DQ ahead)
            float a0 = 0.f, a1 = 0.f, a2 = 0.f;
#pragma unroll
            for (int k = 0; k < 5; ++k) a0 = fmaf(rl(xv, k),      wih[k],      a0);
#pragma unroll
            for (int k = 0; k < 5; ++k) a1 = fmaf(rl(xv, k + 5),  wih[k + 5],  a1);
#pragma unroll
            for (int k = 0; k < 5; ++k) a2 = fmaf(rl(xv, k + 10), wih[k + 10], a2);
            const float xpart = (a0 + a1) + a2;

            // recurrent contribution: two parallel 5-FMA chains off SGPR h
            float a3 = 0.f, a4 = 0.f;
#pragma unroll
            for (int q = 0; q < 5; ++q) a3 = fmaf(hs[q],     whh[q],     a3);
#pragma unroll
            for (int q = 0; q < 5; ++q) a4 = fmaf(hs[q + 5], whh[q + 5], a4);
            const float acc = xpart + (a3 + a4);

            // activation: r = 1/(1+exp2(acc)); sigmoid -> r, tanh -> 1-2r
            const float e   = __builtin_amdgcn_exp2f(acc);
            const float r   = __builtin_amdgcn_rcpf(1.0f + e);
            const float act = fmaf(Aact, r, Bact);

            // gather i,f,g,o of unit j via quad broadcasts (pure VALU)
            const float iv = qb<0x00>(act);
            const float fv = qb<0x55>(act);
            const float gv = qb<0xAA>(act);
            const float ov = qb<0xFF>(act);

            // cell + hidden update (all quad lanes redundantly)
            c = fmaf(fv, c, iv * gv);
            const float tt = __builtin_amdgcn_exp2f(c * (2.0f * LOG2E));
            const float th = fmaf(-2.0f, __builtin_amdgcn_rcpf(1.0f + tt), 1.0f);
            h = ov * th;

            if (writer)
                out[(size_t)t * (B_N * H_N) + b * H_N + j] = h;

            // broadcast new h to SGPRs for next step (unit q at lane 4q)
#pragma unroll
            for (int q = 0; q < H_N; ++q) hs[q] = rl(h, 4 * q);
        }
    }

    // final hN, cN appended after out (flat tuple order: out, hN, cN)
    if (writer) {
        const size_t base = (size_t)T_N * B_N * H_N;
        out[base + b * H_N + j] = h;
        out[base + (size_t)B_N * H_N + b * H_N + j] = c;
    }
}

extern "C" void kernel_launch(void* const* d_in, const int* in_sizes, int n_in,
                              void* d_out, int out_size, void* d_ws, size_t ws_size,
                              hipStream_t stream) {
    const float* x   = (const float*)d_in[0];
    const float* h0  = (const float*)d_in[1];
    const float* c0  = (const float*)d_in[2];
    const float* Wih = (const float*)d_in[3];
    const float* Whh = (const float*)d_in[4];
    float* out = (float*)d_out;
    lstm_fused<<<dim3(B_N), dim3(64), 0, stream>>>(x, h0, c0, Wih, Whh, out);
}